// Round 21
// baseline (65.238 us; speedup 1.0000x reference)
//
#include <hip/hip_runtime.h>

#define BATCH 8
#define NBOX 4096
#define NCLS 80
#define THRESH 0.8f
#define EPSV 1e-9f
#define WAVES 4
#define TPB (WAVES * 64)     // 256 threads
#define PERW (NBOX / WAVES)  // 1024 indices per wave
#define WITER (PERW / 64)    // 16 ballot iterations per wave
#define NCPB 5               // classes per block
#define CBLK (NCLS / NCPB)   // 16 class-chunks
#define WCAP 48              // per-wave per-class cap (mean 12.8, ~10 sd)
#define CCAP 128             // per-class flat cap (mean 51.2, ~11 sd)

// One 4-wave block per (batch, 5-class chunk). Phases:
//  1) register-only ballot compaction of indices for 5 classes
//  2) tid0 builds per-class prefix tables in LDS
//  3) BLOCK-STRIDE flat gather over t in [0, tot)   (tot may exceed TPB!)
//  4) BLOCK-STRIDE all-pairs per class, k ascending original index.
__global__ __launch_bounds__(TPB) void class_filter_kernel(
    const float* __restrict__ boxes,   // [B,N,4]
    const int* __restrict__ cls,       // [B,N]
    float* __restrict__ out)           // [B*N*4] masked boxes, then [B*N] keep
{
    __shared__ int    segIdx[NCPB][WAVES][WCAP];   // 3840 B
    __shared__ int    wcnt[NCPB][WAVES];
    __shared__ int    sPs[NCPB][WAVES + 1];
    __shared__ int    sCum[NCPB + 1];
    __shared__ int    sLen[NCPB];
    __shared__ int    sOvf;
    __shared__ float4 lbox[NCPB * CCAP];           // 10 KiB, flat per class
    __shared__ float2 lai[NCPB * CCAP];            // 5 KiB (area, idx-bits)

    const int b  = blockIdx.x / CBLK;
    const int c0 = (blockIdx.x % CBLK) * NCPB;
    const int tid  = threadIdx.x;
    const int w    = tid >> 6;
    const int lane = tid & 63;
    const int w0   = w * PERW;
    const unsigned long long lmask = (1ull << lane) - 1ull;

    const float4* bx = reinterpret_cast<const float4*>(boxes) + (size_t)b * NBOX;
    const int* cl = cls + (size_t)b * NBOX;

    // prefetch this wave's classes (16 coalesced dword loads, independent)
    int myc[WITER];
#pragma unroll
    for (int it = 0; it < WITER; ++it) myc[it] = cl[w0 + it * 64 + lane];

    // phase 1: 5 ballot chains over the prefetched classes (register-only)
    int run0 = 0, run1 = 0, run2 = 0, run3 = 0, run4 = 0;
#pragma unroll
    for (int it = 0; it < WITER; ++it) {
        const int idx = w0 + it * 64 + lane;
        {
            unsigned long long m = __ballot(myc[it] == c0 + 0);
            int p = run0 + (int)__popcll(m & lmask);
            if ((myc[it] == c0 + 0) && p < WCAP) segIdx[0][w][p] = idx;
            run0 += (int)__popcll(m);
        }
        {
            unsigned long long m = __ballot(myc[it] == c0 + 1);
            int p = run1 + (int)__popcll(m & lmask);
            if ((myc[it] == c0 + 1) && p < WCAP) segIdx[1][w][p] = idx;
            run1 += (int)__popcll(m);
        }
        {
            unsigned long long m = __ballot(myc[it] == c0 + 2);
            int p = run2 + (int)__popcll(m & lmask);
            if ((myc[it] == c0 + 2) && p < WCAP) segIdx[2][w][p] = idx;
            run2 += (int)__popcll(m);
        }
        {
            unsigned long long m = __ballot(myc[it] == c0 + 3);
            int p = run3 + (int)__popcll(m & lmask);
            if ((myc[it] == c0 + 3) && p < WCAP) segIdx[3][w][p] = idx;
            run3 += (int)__popcll(m);
        }
        {
            unsigned long long m = __ballot(myc[it] == c0 + 4);
            int p = run4 + (int)__popcll(m & lmask);
            if ((myc[it] == c0 + 4) && p < WCAP) segIdx[4][w][p] = idx;
            run4 += (int)__popcll(m);
        }
    }
    if (lane == 0) {
        wcnt[0][w] = run0; wcnt[1][w] = run1; wcnt[2][w] = run2;
        wcnt[3][w] = run3; wcnt[4][w] = run4;
    }
    __syncthreads();

    // phase 2: prefix tables (single thread; ~40 LDS ops, once per block)
    if (tid == 0) {
        int cum = 0, ovf = 0;
        for (int cc = 0; cc < NCPB; ++cc) {
            int p = 0;
            sPs[cc][0] = 0;
            for (int ww = 0; ww < WAVES; ++ww) {
                int v = wcnt[cc][ww];
                if (v > WCAP) ovf = 1;
                p += v;
                sPs[cc][ww + 1] = p;
            }
            sLen[cc] = p;
            if (p > CCAP) ovf = 1;
            sCum[cc] = cum;
            cum += p;
        }
        sCum[NCPB] = cum;
        sOvf = ovf;
    }
    __syncthreads();

    float*  keepOut = out + (size_t)BATCH * NBOX * 4;
    float4* boxOut  = reinterpret_cast<float4*>(out);

    if (!sOvf) {
        const int tot = sCum[NCPB];   // may exceed TPB (mean == 256)

        // phase 3: block-stride flat gather (ascending original index per class)
        for (int t = tid; t < tot; t += TPB) {
            int cc = 0;
#pragma unroll
            for (int q = 1; q < NCPB; ++q) if (t >= sCum[q]) cc = q;
            const int r = t - sCum[cc];
            int wsel = 0;
#pragma unroll
            for (int ww = 1; ww < WAVES; ++ww) if (r >= sPs[cc][ww]) wsel = ww;
            const int idx = segIdx[cc][wsel][r - sPs[cc][wsel]];
            float4 bb = bx[idx];
            lbox[cc * CCAP + r] = bb;
            lai[cc * CCAP + r] = make_float2((bb.z - bb.x) * (bb.w - bb.y),
                                             __int_as_float(idx));
        }
        __syncthreads();

        // phase 4: block-stride all-pairs, k ascending (reference FP order)
        for (int t = tid; t < tot; t += TPB) {
            int cc = 0;
#pragma unroll
            for (int q = 1; q < NCPB; ++q) if (t >= sCum[q]) cc = q;
            const int r = t - sCum[cc];
            const float4 bi = lbox[cc * CCAP + r];
            const int mi = __float_as_int(lai[cc * CCAP + r].y);
            const int n = sLen[cc];
            float sum = 0.f;
            for (int k = 0; k < n; ++k) {
                float4 bj = lbox[cc * CCAP + k];
                float2 aj = lai[cc * CCAP + k];
                float m = fmaxf(fmaxf(bi.x - bj.x, bi.y - bj.y),
                                fmaxf(bj.z - bi.z, bj.w - bi.w));
                bool cont = (m <= 0.f) && (__float_as_int(aj.y) != mi);
                sum += cont ? aj.x : 0.f;
            }
            const float area = lai[cc * CCAP + r].x;
            const float kf = (sum <= THRESH * (area + EPSV)) ? 1.f : 0.f;
            const int g = b * NBOX + mi;
            boxOut[g] = make_float4(bi.x * kf, bi.y * kf, bi.z * kf, bi.w * kf);
            keepOut[g] = kf;
        }
    } else {
        // general fallback (never expected): direct global scan for 5 classes
        for (int cc = 0; cc < NCPB; ++cc) {
            const int c = c0 + cc;
            for (int i0 = 0; i0 < NBOX; i0 += TPB) {
                const int i = i0 + tid;
                if (cl[i] != c) continue;
                float4 bi = bx[i];
                float area = (bi.z - bi.x) * (bi.w - bi.y);
                float sum = 0.f;
                for (int j = 0; j < NBOX; ++j) {
                    if (cl[j] != c || j == i) continue;
                    float4 bj = bx[j];
                    float m = fmaxf(fmaxf(bi.x - bj.x, bi.y - bj.y),
                                    fmaxf(bj.z - bi.z, bj.w - bi.w));
                    sum += (m <= 0.f) ? (bj.z - bj.x) * (bj.w - bj.y) : 0.f;
                }
                float kf = (sum <= THRESH * (area + EPSV)) ? 1.f : 0.f;
                const int g = b * NBOX + i;
                boxOut[g] = make_float4(bi.x * kf, bi.y * kf, bi.z * kf, bi.w * kf);
                keepOut[g] = kf;
            }
        }
    }
}

extern "C" void kernel_launch(void* const* d_in, const int* in_sizes, int n_in,
                              void* d_out, int out_size, void* d_ws, size_t ws_size,
                              hipStream_t stream) {
    const float* boxes = (const float*)d_in[0];
    const int*   cls   = (const int*)d_in[1];
    float* out = (float*)d_out;

    class_filter_kernel<<<BATCH * CBLK, TPB, 0, stream>>>(boxes, cls, out);
}

// Round 22
// 59.903 us; speedup vs baseline: 1.0891x; 1.0891x over previous
//
#include <hip/hip_runtime.h>

#define BATCH 8
#define NBOX 4096
#define NCLS 80
#define THRESH 0.8f
#define EPSV 1e-9f
#define WAVES 4
#define TPB (WAVES * 64)     // 256 threads
#define PERW (NBOX / WAVES)  // 1024 indices per wave
#define WITER (PERW / 64)    // 16 ballot iterations per wave
#define WCAP 96              // per-wave cap (mean 12.8/quarter, ~23 sd margin)
#define LCAP (WAVES * WCAP)  // 384 flat capacity

// One 4-wave block per (batch, class), three phases (best measured: 59.9us):
//  1) ballot-compact ORIGINAL INDICES into wave-local LDS segments (register-
//     only chain: classes prefetched, no global loads inside the chain)
//  2) flat gather: thread t < len loads box[segIdx[t]] -- all scattered loads
//     issued in parallel -- into flat LDS arrays (ascending original index)
//  3) all-pairs over the flat segment, exact j != i by index; direct output.
__global__ __launch_bounds__(TPB) void class_filter_kernel(
    const float* __restrict__ boxes,   // [B,N,4]
    const int* __restrict__ cls,       // [B,N]
    float* __restrict__ out)           // [B*N*4] masked boxes, then [B*N] keep
{
    __shared__ int    segIdx[LCAP];    // wave-segmented original indices
    __shared__ int    wcnt[WAVES];
    __shared__ float4 lbox[LCAP];      // flat, ascending original index
    __shared__ float2 lai[LCAP];       // (area, idx-bits) packed -> 1 b64 read

    const int b = blockIdx.x / NCLS;
    const int c = blockIdx.x % NCLS;
    const int tid  = threadIdx.x;
    const int w    = tid >> 6;
    const int lane = tid & 63;
    const int w0   = w * PERW;

    const float4* bx = reinterpret_cast<const float4*>(boxes) + (size_t)b * NBOX;
    const int* cl = cls + (size_t)b * NBOX;

    // prefetch this wave's classes (16 coalesced dword loads, all independent)
    int myc[WITER];
#pragma unroll
    for (int it = 0; it < WITER; ++it) myc[it] = cl[w0 + it * 64 + lane];

    // phase 1: register-only ballot compaction of indices
    int run = 0;
#pragma unroll
    for (int it = 0; it < WITER; ++it) {
        const bool m = (myc[it] == c);
        const unsigned long long mask = __ballot(m);
        const int pos = run + (int)__popcll(mask & ((1ull << lane) - 1ull));
        if (m && pos < WCAP) segIdx[w * WCAP + pos] = w0 + it * 64 + lane;
        run += (int)__popcll(mask);
    }
    if (lane == 0) wcnt[w] = run;
    __syncthreads();

    int psum[WAVES + 1];
    psum[0] = 0;
    bool ovf = false;
#pragma unroll
    for (int ww = 0; ww < WAVES; ++ww) {
        int v = wcnt[ww];
        ovf |= (v > WCAP);
        psum[ww + 1] = psum[ww] + v;
    }
    const int len = psum[WAVES];   // <= LCAP = 384 when !ovf

    float*  keepOut = out + (size_t)BATCH * NBOX * 4;
    float4* boxOut  = reinterpret_cast<float4*>(out);

    if (!ovf) {
        // phase 2: parallel flat gather (one scattered load per matched box)
        if (tid < len) {
            int wsel = 0;
#pragma unroll
            for (int ww = 1; ww < WAVES; ++ww) if (tid >= psum[ww]) wsel = ww;
            const int idx = segIdx[wsel * WCAP + (tid - psum[wsel])];
            float4 bb = bx[idx];
            lbox[tid] = bb;
            lai[tid]  = make_float2((bb.z - bb.x) * (bb.w - bb.y),
                                    __int_as_float(idx));
        }
        __syncthreads();

        // phase 3: all-pairs, k ascending original index (reference FP order)
        if (tid < len) {
            const float4 bi = lbox[tid];
            const int mi = __float_as_int(lai[tid].y);
            float sum = 0.f;
            for (int k = 0; k < len; ++k) {          // broadcast LDS reads
                float4 bj = lbox[k];
                float2 aj = lai[k];
                float m = fmaxf(fmaxf(bi.x - bj.x, bi.y - bj.y),
                                fmaxf(bj.z - bi.z, bj.w - bi.w));
                bool cont = (m <= 0.f) && (__float_as_int(aj.y) != mi);
                sum += cont ? aj.x : 0.f;
            }
            const float area = lai[tid].x;
            const float kf = (sum <= THRESH * (area + EPSV)) ? 1.f : 0.f;
            const int g = b * NBOX + mi;
            boxOut[g] = make_float4(bi.x * kf, bi.y * kf, bi.z * kf, bi.w * kf);
            keepOut[g] = kf;
        }
    } else {
        // general fallback (not expected with this input): direct global scan
        for (int i0 = 0; i0 < NBOX; i0 += TPB) {
            const int i = i0 + tid;
            if (cl[i] != c) continue;
            float4 bi = bx[i];
            float area = (bi.z - bi.x) * (bi.w - bi.y);
            float sum = 0.f;
            for (int j = 0; j < NBOX; ++j) {
                if (cl[j] != c || j == i) continue;
                float4 bj = bx[j];
                float m = fmaxf(fmaxf(bi.x - bj.x, bi.y - bj.y),
                                fmaxf(bj.z - bi.z, bj.w - bi.w));
                sum += (m <= 0.f) ? (bj.z - bj.x) * (bj.w - bj.y) : 0.f;
            }
            float kf = (sum <= THRESH * (area + EPSV)) ? 1.f : 0.f;
            const int g = b * NBOX + i;
            boxOut[g] = make_float4(bi.x * kf, bi.y * kf, bi.z * kf, bi.w * kf);
            keepOut[g] = kf;
        }
    }
}

extern "C" void kernel_launch(void* const* d_in, const int* in_sizes, int n_in,
                              void* d_out, int out_size, void* d_ws, size_t ws_size,
                              hipStream_t stream) {
    const float* boxes = (const float*)d_in[0];
    const int*   cls   = (const int*)d_in[1];
    float* out = (float*)d_out;

    class_filter_kernel<<<BATCH * NCLS, TPB, 0, stream>>>(boxes, cls, out);
}